// Round 1
// baseline (299.621 us; speedup 1.0000x reference)
//
#include <hip/hip_runtime.h>

// Problem constants from the reference: B,C,H,W = 32,1,720,1280
constexpr int Bn = 32;
constexpr int Hn = 720;
constexpr int Wn = 1280;

// One thread handles 4 consecutive pixels (same row since W % 4 == 0):
// float4 disp load, float4 out store, 16 scalar gathers from a local window.
__global__ __launch_bounds__(256) void warp_kernel(
    const float* __restrict__ img,
    const float* __restrict__ disp,
    float* __restrict__ out)
{
    const int hw = Hn * Wn;
    const long long total4 = (long long)Bn * hw / 4;
    long long t = (long long)blockIdx.x * blockDim.x + threadIdx.x;
    if (t >= total4) return;
    long long base = t * 4;               // flat pixel index of first of 4

    int b   = (int)(base / hw);
    int rem = (int)(base % hw);
    int y   = rem / Wn;
    int x   = rem - y * Wn;               // aligned to 4

    // ---- per-row vertical coordinate (align_corners=False grid_sample) ----
    float gy  = (((float)y - (float)(Hn - 1) * 0.5f) / (float)(Hn - 1)) * 2.0f;
    float iy  = ((gy + 1.0f) * (float)Hn - 1.0f) * 0.5f;
    float fy0 = floorf(iy);
    float wy1 = iy - fy0;
    float wy0 = 1.0f - wy1;
    int   y0  = (int)fy0;
    int   y1  = y0 + 1;
    bool  vy0 = (y0 >= 0) && (y0 < Hn);
    bool  vy1 = (y1 >= 0) && (y1 < Hn);
    int   y0c = min(max(y0, 0), Hn - 1);
    int   y1c = min(max(y1, 0), Hn - 1);

    const float* __restrict__ imb  = img + (long long)b * hw;
    const float* __restrict__ row0 = imb + (long long)y0c * Wn;
    const float* __restrict__ row1 = imb + (long long)y1c * Wn;

    const float4 d4 = *reinterpret_cast<const float4*>(disp + base);
    float dv[4] = {d4.x, d4.y, d4.z, d4.w};
    float res[4];

#pragma unroll
    for (int i = 0; i < 4; ++i) {
        float xf  = (float)(x + i);
        // gx = ((x - disp) - (W-1)/2) / (W-1) * 2 ; ix = ((gx+1)*W - 1)/2
        float gx  = ((xf - dv[i] - (float)(Wn - 1) * 0.5f) / (float)(Wn - 1)) * 2.0f;
        float ix  = ((gx + 1.0f) * (float)Wn - 1.0f) * 0.5f;
        float fx0 = floorf(ix);
        float wx1 = ix - fx0;
        float wx0 = 1.0f - wx1;
        int   x0  = (int)fx0;
        int   x1  = x0 + 1;
        bool  vx0 = (x0 >= 0) && (x0 < Wn);
        bool  vx1 = (x1 >= 0) && (x1 < Wn);
        int   x0c = min(max(x0, 0), Wn - 1);
        int   x1c = min(max(x1, 0), Wn - 1);

        // clamped loads (always in-bounds) x validity mask, like the reference
        float m00 = (vy0 && vx0) ? 1.0f : 0.0f;
        float m01 = (vy0 && vx1) ? 1.0f : 0.0f;
        float m10 = (vy1 && vx0) ? 1.0f : 0.0f;
        float m11 = (vy1 && vx1) ? 1.0f : 0.0f;

        float v00 = row0[x0c] * m00;
        float v01 = row0[x1c] * m01;
        float v10 = row1[x0c] * m10;
        float v11 = row1[x1c] * m11;

        res[i] = v00 * (wy0 * wx0) + v01 * (wy0 * wx1)
               + v10 * (wy1 * wx0) + v11 * (wy1 * wx1);
    }

    float4 o4 = make_float4(res[0], res[1], res[2], res[3]);
    *reinterpret_cast<float4*>(out + base) = o4;
}

extern "C" void kernel_launch(void* const* d_in, const int* in_sizes, int n_in,
                              void* d_out, int out_size, void* d_ws, size_t ws_size,
                              hipStream_t stream) {
    const float* img  = (const float*)d_in[0];   // right_img [32,1,720,1280] fp32
    const float* disp = (const float*)d_in[1];   // disp      [32,1,720,1280] fp32
    float* out = (float*)d_out;                  // [32,1,720,1280] fp32

    const long long total4 = (long long)Bn * Hn * Wn / 4;   // 7,372,800 threads
    const int block = 256;
    const int grid  = (int)((total4 + block - 1) / block);  // 28,800 blocks

    warp_kernel<<<grid, block, 0, stream>>>(img, disp, out);
}

// Round 2
// 271.526 us; speedup vs baseline: 1.1035x; 1.1035x over previous
//
#include <hip/hip_runtime.h>

// Problem constants from the reference: B,C,H,W = 32,1,720,1280
constexpr int Bn = 32;
constexpr int Hn = 720;
constexpr int Wn = 1280;

// One block = one output row (b, y). 320 threads x 4 px = 1280 = W.
// Stage the two source image rows (y0c, y1c) in LDS with coalesced float4
// loads, then do bilinear gathers as LDS reads (x0c, x0c+1 pairs).
__global__ __launch_bounds__(320) void warp_kernel(
    const float* __restrict__ img,
    const float* __restrict__ disp,
    float* __restrict__ out)
{
    __shared__ float srow[2 * Wn];     // 10240 B

    const int hw  = Hn * Wn;
    const int blk = blockIdx.x;        // b * Hn + y
    const int b   = blk / Hn;
    const int y   = blk - b * Hn;
    const int tid = threadIdx.x;

    // ---- per-row vertical coordinate (align_corners=False grid_sample) ----
    // Block-uniform: stays scalar.
    float gy  = (((float)y - (float)(Hn - 1) * 0.5f) / (float)(Hn - 1)) * 2.0f;
    float iy  = ((gy + 1.0f) * (float)Hn - 1.0f) * 0.5f;
    float fy0 = floorf(iy);
    float wy1 = iy - fy0;
    float wy0 = 1.0f - wy1;
    int   y0  = (int)fy0;
    int   y1  = y0 + 1;
    bool  vy0 = (y0 >= 0) && (y0 < Hn);
    bool  vy1 = (y1 >= 0) && (y1 < Hn);
    int   y0c = min(max(y0, 0), Hn - 1);
    int   y1c = min(max(y1, 0), Hn - 1);

    const float* __restrict__ imb = img + (long long)b * hw;

    // ---- stage rows y0c and y1c into LDS (coalesced float4) ----
    {
        const float4* __restrict__ src0 = reinterpret_cast<const float4*>(imb + (long long)y0c * Wn);
        const float4* __restrict__ src1 = reinterpret_cast<const float4*>(imb + (long long)y1c * Wn);
        float4* dst = reinterpret_cast<float4*>(srow);
        dst[tid]       = src0[tid];    // floats [0, 1280)
        dst[320 + tid] = src1[tid];    // floats [1280, 2560)
    }
    __syncthreads();

    const float* __restrict__ r0 = srow;        // row y0c
    const float* __restrict__ r1 = srow + Wn;   // row y1c

    const long long base = (long long)blk * Wn + 4 * tid;  // flat pixel index
    const float4 d4 = *reinterpret_cast<const float4*>(disp + base);
    float dv[4] = {d4.x, d4.y, d4.z, d4.w};
    float res[4];

    const float my0 = vy0 ? 1.0f : 0.0f;   // y always in-bounds for this grid,
    const float my1 = vy1 ? 1.0f : 0.0f;   // kept for exact reference semantics

#pragma unroll
    for (int i = 0; i < 4; ++i) {
        float xf  = (float)(4 * tid + i);
        float gx  = ((xf - dv[i] - (float)(Wn - 1) * 0.5f) / (float)(Wn - 1)) * 2.0f;
        float ix  = ((gx + 1.0f) * (float)Wn - 1.0f) * 0.5f;
        float fx0 = floorf(ix);
        float wx1 = ix - fx0;
        float wx0 = 1.0f - wx1;
        int   x0  = (int)fx0;
        int   x1  = x0 + 1;
        float mx0 = ((x0 >= 0) && (x0 < Wn)) ? 1.0f : 0.0f;
        float mx1 = ((x1 >= 0) && (x1 < Wn)) ? 1.0f : 0.0f;
        int   x0c = min(max(x0, 0), Wn - 1);
        int   x1c = min(max(x1, 0), Wn - 1);

        // LDS gathers; v00/v01 (and v10/v11) are adjacent -> ds_read2_b32
        float v00 = r0[x0c] * (my0 * mx0);
        float v01 = r0[x1c] * (my0 * mx1);
        float v10 = r1[x0c] * (my1 * mx0);
        float v11 = r1[x1c] * (my1 * mx1);

        res[i] = v00 * (wy0 * wx0) + v01 * (wy0 * wx1)
               + v10 * (wy1 * wx0) + v11 * (wy1 * wx1);
    }

    float4 o4 = make_float4(res[0], res[1], res[2], res[3]);
    *reinterpret_cast<float4*>(out + base) = o4;
}

extern "C" void kernel_launch(void* const* d_in, const int* in_sizes, int n_in,
                              void* d_out, int out_size, void* d_ws, size_t ws_size,
                              hipStream_t stream) {
    const float* img  = (const float*)d_in[0];   // right_img [32,1,720,1280] fp32
    const float* disp = (const float*)d_in[1];   // disp      [32,1,720,1280] fp32
    float* out = (float*)d_out;                  // [32,1,720,1280] fp32

    const int grid  = Bn * Hn;   // 23040 blocks, one per output row
    const int block = 320;       // 5 waves; 4 px/thread covers W=1280

    warp_kernel<<<grid, block, 0, stream>>>(img, disp, out);
}